// Round 14
// baseline (195.034 us; speedup 1.0000x reference)
//
#include <hip/hip_runtime.h>

typedef __attribute__((ext_vector_type(8))) __bf16 bf8;
typedef __attribute__((ext_vector_type(4))) float f4;
typedef __attribute__((ext_vector_type(8))) unsigned short us8;
typedef __attribute__((ext_vector_type(4))) unsigned short us4;
typedef __attribute__((ext_vector_type(4))) unsigned int u32x4;
typedef __attribute__((ext_vector_type(2))) unsigned int u32x2;

#define MFMA16(a, b, c) __builtin_amdgcn_mfma_f32_16x16x32_bf16((a), (b), (c), 0, 0, 0)
#define GLOAD16(gp, lp)                                                        \
  __builtin_amdgcn_global_load_lds(                                            \
      (const __attribute__((address_space(1))) void*)(gp),                     \
      (__attribute__((address_space(3))) void*)(lp), 16, 0, 0)

__device__ __forceinline__ unsigned short f2bf(float f) {
  unsigned u = __builtin_bit_cast(unsigned, f);
  u += 0x7FFFu + ((u >> 16) & 1u);
  return (unsigned short)(u >> 16);
}

__device__ __forceinline__ float fexp2(float x) {
  float r;
  asm("v_exp_f32 %0, %1" : "=v"(r) : "v"(x));
  return r;
}

// dst.lo = bf16(a), dst.hi = bf16(b)  (RNE, identical to f2bf)
__device__ __forceinline__ unsigned cvtpk(float a, float b) {
  unsigned r;
  asm("v_cvt_pk_bf16_f32 %0, %1, %2" : "=v"(r) : "v"(a), "v"(b));
  return r;
}

// ---------------- merged prologue: cast + both weight transposes ----------
__global__ __launch_bounds__(256) void c_prep(const float* __restrict__ hs,
                                              unsigned short* __restrict__ hsb,
                                              const float* __restrict__ wqkv,
                                              unsigned short* __restrict__ wqt,
                                              const float* __restrict__ wout,
                                              unsigned short* __restrict__ wot) {
  __shared__ float T[64][65];
  const int bid = blockIdx.x;
  const int t = threadIdx.x;
  if (bid < 4096) {
    int i = bid * 256 + t;
    const float4* p = reinterpret_cast<const float4*>(hs) + (size_t)i * 2;
    float4 a = p[0], b = p[1];
    u32x4 o;
    o[0] = cvtpk(a.x, a.y);
    o[1] = cvtpk(a.z, a.w);
    o[2] = cvtpk(b.x, b.y);
    o[3] = cvtpk(b.z, b.w);
    *reinterpret_cast<u32x4*>(&hsb[(size_t)i * 8]) = o;
    return;
  }
  const float* in;
  unsigned short* out;
  int R = 1024, C, idx;
  if (bid < 4864) { idx = bid - 4096; in = wqkv; out = wqt; C = 3072; }
  else            { idx = bid - 4864; in = wout; out = wot; C = 1024; }
  const int nbc = C >> 6;
  const int c0 = (idx % nbc) * 64, r0 = (idx / nbc) * 64;
  const int tr = t >> 4, tc = (t & 15) * 4;
#pragma unroll
  for (int i = 0; i < 4; ++i) {
    int r = tr + i * 16;
    float4 v = *reinterpret_cast<const float4*>(&in[(size_t)(r0 + r) * C + c0 + tc]);
    T[r][tc] = v.x; T[r][tc + 1] = v.y; T[r][tc + 2] = v.z; T[r][tc + 3] = v.w;
  }
  __syncthreads();
#pragma unroll
  for (int i = 0; i < 4; ++i) {
    int c = tr + i * 16;
    u32x2 o;
    o[0] = cvtpk(T[tc + 0][c], T[tc + 1][c]);
    o[1] = cvtpk(T[tc + 2][c], T[tc + 3][c]);
    *reinterpret_cast<u32x2*>(&out[(size_t)(c0 + c) * R + r0 + tc]) = o;
  }
}

// ---------------- Kernel 1: QKV projection GEMM (4-slot ring) -------------
// Q pre-scaled by 0.125*log2(e). V stored TRANSPOSED + quad-PAIRED:
// Vt[bh][d][pos(s)], pair p holds quads [q, q+4] adjacently (16B).
// 4-slot LDS ring, 2 K-tiles per barrier period. 1D grid 1536, XCD-swizzled.
__global__ __launch_bounds__(256) void k_qkv(const unsigned short* __restrict__ A,
                                             const unsigned short* __restrict__ Bt,
                                             unsigned short* __restrict__ Qo,
                                             unsigned short* __restrict__ Ko,
                                             unsigned short* __restrict__ Vo) {
  __shared__ unsigned short As[4][128 * 32];
  __shared__ unsigned short Bs[4][128 * 32];
  const int t = threadIdx.x;
  const int lane = t & 63, wid = t >> 6;
  const int wr = wid >> 1, wc = wid & 1;
  const int cl = lane & 15, kr8 = (lane >> 4) << 3;
  const int id = blockIdx.x;
  const int s = (id & 7) * 192 + (id >> 3);
  const int m0 = (s / 24) << 7, n0 = (s % 24) << 7;

  f4 acc[4][4];
#pragma unroll
  for (int i = 0; i < 4; ++i)
#pragma unroll
    for (int j = 0; j < 4; ++j) acc[i][j] = (f4){0.f, 0.f, 0.f, 0.f};

  auto STAGE = [&](int slot, int kt) {
    int k0 = kt << 5;
#pragma unroll
    for (int it = 0; it < 2; ++it) {
      int c = t + (it << 8);
      int wb = (t & 192) + (it << 8);
      GLOAD16(A + (size_t)(m0 + (c >> 2)) * 1024 + k0 + ((c & 3) << 3),
              (char*)As[slot] + (size_t)wb * 16);
      GLOAD16(Bt + (size_t)(n0 + (c >> 2)) * 1024 + k0 + ((c & 3) << 3),
              (char*)Bs[slot] + (size_t)wb * 16);
    }
  };

  auto COMPUTE = [&](int slot) {
    const unsigned short* as = As[slot];
    const unsigned short* bs = Bs[slot];
    bf8 af[4], bfr[4];
#pragma unroll
    for (int mi = 0; mi < 4; ++mi)
      af[mi] = *reinterpret_cast<const bf8*>(&as[(wr * 64 + mi * 16 + cl) * 32 + kr8]);
#pragma unroll
    for (int ni = 0; ni < 4; ++ni)
      bfr[ni] = *reinterpret_cast<const bf8*>(&bs[(wc * 64 + ni * 16 + cl) * 32 + kr8]);
#pragma unroll
    for (int mi = 0; mi < 4; ++mi)
#pragma unroll
      for (int ni = 0; ni < 4; ++ni)
        acc[mi][ni] = MFMA16(af[mi], bfr[ni], acc[mi][ni]);
  };

  STAGE(0, 0);
  STAGE(1, 1);
  __syncthreads();
  for (int ti = 0; ti < 16; ++ti) {
    int t0 = 2 * ti, t1 = t0 + 1;
    if (ti < 15) {
      STAGE((t0 + 2) & 3, t0 + 2);
      STAGE((t1 + 2) & 3, t1 + 2);
    }
    COMPUTE(t0 & 3);
    COMPUTE(t1 & 3);
    __syncthreads();
  }

#pragma unroll
  for (int mi = 0; mi < 4; ++mi) {
#pragma unroll
    for (int ni = 0; ni < 4; ++ni) {
      int gcol = n0 + wc * 64 + ni * 16 + cl;
      int grow0 = m0 + wr * 64 + mi * 16 + ((lane >> 4) << 2);
      int b = grow0 >> 11, s0 = grow0 & 2047;
      if (gcol < 1024) {
        int h = gcol >> 6, hd = gcol & 63;
#pragma unroll
        for (int r = 0; r < 4; ++r)
          Qo[((size_t)(b * 16 + h) * 2048 + s0 + r) * 64 + hd] =
              f2bf(acc[mi][ni][r] * 0.18033688011112042f);  // 0.125*log2(e)
      } else if (gcol < 2048) {
        int cc = gcol - 1024;
        int h = cc >> 6, hd = cc & 63;
#pragma unroll
        for (int r = 0; r < 4; ++r)
          Ko[((size_t)(b * 16 + h) * 2048 + s0 + r) * 64 + hd] = f2bf(acc[mi][ni][r]);
      } else {
        int cc = gcol - 2048;
        int h = cc >> 6, hd = cc & 63;
        us4 o;
        o[0] = f2bf(acc[mi][ni][0]); o[1] = f2bf(acc[mi][ni][1]);
        o[2] = f2bf(acc[mi][ni][2]); o[3] = f2bf(acc[mi][ni][3]);
        // quad-pair interleave: pair p holds quads (8kg+gg, 8kg+gg+4).
        int q = (s0 >> 2) & 15;
        int kg2 = q >> 3, w = q & 7;
        int first = (w < 4) ? 1 : 0;
        int gg = first ? w : (w - 4);
        int p = 4 * kg2 + gg;
        int npos = (s0 & ~63) | (p << 3) | (first ? 0 : 4);
        *reinterpret_cast<us4*>(&Vo[((size_t)(b * 16 + h) * 64 + hd) * 2048 + npos]) = o;
      }
    }
  }
}

// ---------------- Kernel 2: flash attention (round-13, frozen) ------------
__global__ __launch_bounds__(512) void k_attn(const unsigned short* __restrict__ Q,
                                              const unsigned short* __restrict__ K,
                                              const unsigned short* __restrict__ Vt,
                                              unsigned short* __restrict__ Ctx) {
  __shared__ __align__(16) unsigned short SMEM[4][2][64 * 64];  // [slot][K/V]
  __shared__ float RedS[128];
  const int t = threadIdx.x;
  const int lane = t & 63, wid = t >> 6;
  const int cl = lane & 15, g = lane >> 4;
  const int qg = wid >> 1, kg = wid & 1;
  const int id = blockIdx.x;
  const int sw = (id & 7) * 128 + (id >> 3);
  const int bh = sw >> 4, qb = sw & 15;
  const int b = bh >> 4, h = bh & 15;
  const int q0 = qb << 7;
  const size_t base = (size_t)bh * (2048 * 64);

  bf8 qf[2][2];
#pragma unroll
  for (int qi = 0; qi < 2; ++qi) {
    int qrow = q0 + qg * 32 + qi * 16 + cl;
    qf[qi][0] = *reinterpret_cast<const bf8*>(&Q[base + (size_t)qrow * 64 + (g << 3)]);
    qf[qi][1] = *reinterpret_cast<const bf8*>(&Q[base + (size_t)qrow * 64 + 32 + (g << 3)]);
  }

  const unsigned ones_u = 0x3F803F80u;
  u32x4 ones4 = (u32x4){ones_u, ones_u, ones_u, ones_u};
  bf8 onesb = __builtin_bit_cast(bf8, ones4);
  const f4 minit = (f4){-12.f, -12.f, -12.f, -12.f};

  f4 o[2][4], osum[2];
#pragma unroll
  for (int qi = 0; qi < 2; ++qi) {
#pragma unroll
    for (int n = 0; n < 4; ++n) o[qi][n] = (f4){0.f, 0.f, 0.f, 0.f};
    osum[qi] = (f4){0.f, 0.f, 0.f, 0.f};
  }

  auto STAGEK = [&](int slot, int kv0) {
    int kvl = t >> 3;
    int dblk = (t & 7) ^ (kvl & 7);
    GLOAD16(K + base + (size_t)(kv0 + kvl) * 64 + (dblk << 3),
            (char*)SMEM[slot][0] + (size_t)(t & 448) * 16);
  };
  auto STAGEV = [&](int slot, int kv0) {
    int d = t >> 3, sp = t & 7;
    int p = sp ^ (d & 7);
    GLOAD16(Vt + base + (size_t)d * 2048 + kv0 + (p << 3),
            (char*)SMEM[slot][1] + (size_t)(t & 448) * 16);
  };

  auto COMPUTE = [&](const char* kp, const char* vp) {
    f4 sT[2][2];
    __builtin_amdgcn_s_setprio(1);
#pragma unroll
    for (int cb = 0; cb < 2; ++cb) {
      int row = (2 * kg + cb) * 16 + cl;
      bf8 a0 = *reinterpret_cast<const bf8*>(kp + row * 128 + ((g ^ (cl & 7)) << 4));
      bf8 a1 = *reinterpret_cast<const bf8*>(kp + row * 128 + (((4 + g) ^ (cl & 7)) << 4));
#pragma unroll
      for (int qi = 0; qi < 2; ++qi) {
        f4 s = minit;
        s = MFMA16(a0, qf[qi][0], s);
        s = MFMA16(a1, qf[qi][1], s);
        sT[cb][qi] = s;
      }
    }
    __builtin_amdgcn_s_setprio(0);

    u32x4 pw[2];
#pragma unroll
    for (int qi = 0; qi < 2; ++qi) {
      pw[qi][0] = cvtpk(fexp2(sT[0][qi][0]), fexp2(sT[0][qi][1]));
      pw[qi][1] = cvtpk(fexp2(sT[0][qi][2]), fexp2(sT[0][qi][3]));
      pw[qi][2] = cvtpk(fexp2(sT[1][qi][0]), fexp2(sT[1][qi][1]));
      pw[qi][3] = cvtpk(fexp2(sT[1][qi][2]), fexp2(sT[1][qi][3]));
    }
    bf8 pa0 = __builtin_bit_cast(bf8, pw[0]);
    bf8 pa1 = __builtin_bit_cast(bf8, pw[1]);

    const unsigned vb = (unsigned)(cl * 128) + (unsigned)(((4 * kg + g) ^ (cl & 7)) << 4);
    __builtin_amdgcn_s_setprio(1);
#pragma unroll
    for (int n = 0; n < 4; ++n) {
      bf8 vb8 = *reinterpret_cast<const bf8*>(vp + vb + n * 2048);
      o[0][n] = MFMA16(pa0, vb8, o[0][n]);
      o[1][n] = MFMA16(pa1, vb8, o[1][n]);
    }
    osum[0] = MFMA16(pa0, onesb, osum[0]);
    osum[1] = MFMA16(pa1, onesb, osum[1]);
    __builtin_amdgcn_s_setprio(0);
  };

  STAGEK(0, 0);
  STAGEV(0, 0);
  STAGEK(1, 64);
  STAGEV(1, 64);
  __syncthreads();

  for (int ti = 0; ti < 16; ++ti) {
    int t0 = 2 * ti, t1 = t0 + 1;
    if (ti < 15) {
      STAGEK((t0 + 2) & 3, (t0 + 2) << 6);
      STAGEV((t0 + 2) & 3, (t0 + 2) << 6);
      STAGEK((t1 + 2) & 3, (t1 + 2) << 6);
      STAGEV((t1 + 2) & 3, (t1 + 2) << 6);
    }
    COMPUTE((const char*)SMEM[t0 & 3][0], (const char*)SMEM[t0 & 3][1]);
    COMPUTE((const char*)SMEM[t1 & 3][0], (const char*)SMEM[t1 & 3][1]);
    __syncthreads();
  }

  float* red = (float*)SMEM;
  if (kg) {
#pragma unroll
    for (int qi = 0; qi < 2; ++qi) {
#pragma unroll
      for (int n = 0; n < 4; ++n) {
        int ridx = qg * 8 + qi * 4 + n;
        *reinterpret_cast<f4*>(red + ridx * 256 + cl * 16 + g * 4) = o[qi][n];
      }
      if (cl == 0)
        *reinterpret_cast<f4*>(&RedS[(qg * 2 + qi) * 16 + g * 4]) = osum[qi];
    }
  }
  __syncthreads();
  if (!kg) {
#pragma unroll
    for (int qi = 0; qi < 2; ++qi) {
#pragma unroll
      for (int n = 0; n < 4; ++n) {
        int ridx = qg * 8 + qi * 4 + n;
        f4 po = *reinterpret_cast<const f4*>(red + ridx * 256 + cl * 16 + g * 4);
        o[qi][n] += po;
      }
      f4 ps = *reinterpret_cast<const f4*>(&RedS[(qg * 2 + qi) * 16 + g * 4]);
      osum[qi] += ps;
#pragma unroll
      for (int r = 0; r < 4; ++r) {
        float inv = 1.0f / osum[qi][r];
        int sq = q0 + qg * 32 + qi * 16 + (g << 2) + r;
        size_t rb = ((size_t)b * 2048 + sq) * 1024 + h * 64;
#pragma unroll
        for (int n = 0; n < 4; ++n) Ctx[rb + n * 16 + cl] = f2bf(o[qi][n][r] * inv);
      }
    }
  }
}

// ---------------- Kernel 3: output projection GEMM (4-slot ring) ----------
__global__ __launch_bounds__(256) void k_oproj(const unsigned short* __restrict__ A,
                                               const unsigned short* __restrict__ Bt,
                                               float* __restrict__ Out) {
  __shared__ unsigned short As[4][128 * 32];
  __shared__ unsigned short Bs[4][128 * 32];
  const int t = threadIdx.x;
  const int lane = t & 63, wid = t >> 6;
  const int wr = wid >> 1, wc = wid & 1;
  const int cl = lane & 15, kr8 = (lane >> 4) << 3;
  const int id = blockIdx.x;
  const int s = (id & 7) * 64 + (id >> 3);
  const int m0 = (s >> 3) << 7, n0 = (s & 7) << 7;

  f4 acc[4][4];
#pragma unroll
  for (int i = 0; i < 4; ++i)
#pragma unroll
    for (int j = 0; j < 4; ++j) acc[i][j] = (f4){0.f, 0.f, 0.f, 0.f};

  auto STAGE = [&](int slot, int kt) {
    int k0 = kt << 5;
#pragma unroll
    for (int it = 0; it < 2; ++it) {
      int c = t + (it << 8);
      int wb = (t & 192) + (it << 8);
      GLOAD16(A + (size_t)(m0 + (c >> 2)) * 1024 + k0 + ((c & 3) << 3),
              (char*)As[slot] + (size_t)wb * 16);
      GLOAD16(Bt + (size_t)(n0 + (c >> 2)) * 1024 + k0 + ((c & 3) << 3),
              (char*)Bs[slot] + (size_t)wb * 16);
    }
  };

  auto COMPUTE = [&](int slot) {
    const unsigned short* as = As[slot];
    const unsigned short* bs = Bs[slot];
    bf8 af[4], bfr[4];
#pragma unroll
    for (int mi = 0; mi < 4; ++mi)
      af[mi] = *reinterpret_cast<const bf8*>(&as[(wr * 64 + mi * 16 + cl) * 32 + kr8]);
#pragma unroll
    for (int ni = 0; ni < 4; ++ni)
      bfr[ni] = *reinterpret_cast<const bf8*>(&bs[(wc * 64 + ni * 16 + cl) * 32 + kr8]);
#pragma unroll
    for (int mi = 0; mi < 4; ++mi)
#pragma unroll
      for (int ni = 0; ni < 4; ++ni)
        acc[mi][ni] = MFMA16(af[mi], bfr[ni], acc[mi][ni]);
  };

  STAGE(0, 0);
  STAGE(1, 1);
  __syncthreads();
  for (int ti = 0; ti < 16; ++ti) {
    int t0 = 2 * ti, t1 = t0 + 1;
    if (ti < 15) {
      STAGE((t0 + 2) & 3, t0 + 2);
      STAGE((t1 + 2) & 3, t1 + 2);
    }
    COMPUTE(t0 & 3);
    COMPUTE(t1 & 3);
    __syncthreads();
  }

#pragma unroll
  for (int mi = 0; mi < 4; ++mi) {
#pragma unroll
    for (int ni = 0; ni < 4; ++ni) {
      int gcol = n0 + wc * 64 + ni * 16 + cl;
#pragma unroll
      for (int r = 0; r < 4; ++r) {
        int grow = m0 + wr * 64 + mi * 16 + ((lane >> 4) << 2) + r;
        Out[(size_t)grow * 1024 + gcol] = acc[mi][ni][r];
      }
    }
  }
}

extern "C" void kernel_launch(void* const* d_in, const int* in_sizes, int n_in,
                              void* d_out, int out_size, void* d_ws, size_t ws_size,
                              hipStream_t stream) {
  const float* hs = (const float*)d_in[0];
  const float* wqkv = (const float*)d_in[1];
  const float* wout = (const float*)d_in[2];
  float* out = (float*)d_out;

  unsigned short* ws = (unsigned short*)d_ws;
  const size_t NHS = (size_t)8192 * 1024;
  const size_t NWQ = (size_t)1024 * 3072;
  const size_t NWO = (size_t)1024 * 1024;
  const size_t NQ = (size_t)64 * 2048 * 64;

  unsigned short* hsb = ws;
  unsigned short* wqt = ws + NHS;
  unsigned short* wot = wqt + NWQ;
  unsigned short* Qw = wot + NWO;
  unsigned short* Kw = Qw + NQ;
  unsigned short* Vw = Kw + NQ;   // Vt layout [bh][64][2048], quad-paired
  unsigned short* Cw = hsb;       // hs dead after k_qkv

  c_prep<<<dim3(5120), 256, 0, stream>>>(hs, hsb, wqkv, wqt, wout, wot);
  k_qkv<<<dim3(1536), 256, 0, stream>>>(hsb, wqt, Qw, Kw, Vw);
  k_attn<<<dim3(1024), 512, 0, stream>>>(Qw, Kw, Vw, Cw);
  k_oproj<<<dim3(512), 256, 0, stream>>>(Cw, wot, out);
}

// Round 15
// 182.706 us; speedup vs baseline: 1.0675x; 1.0675x over previous
//
#include <hip/hip_runtime.h>

typedef __attribute__((ext_vector_type(8))) __bf16 bf8;
typedef __attribute__((ext_vector_type(4))) float f4;
typedef __attribute__((ext_vector_type(8))) unsigned short us8;
typedef __attribute__((ext_vector_type(4))) unsigned short us4;
typedef __attribute__((ext_vector_type(4))) unsigned int u32x4;
typedef __attribute__((ext_vector_type(2))) unsigned int u32x2;

#define MFMA16(a, b, c) __builtin_amdgcn_mfma_f32_16x16x32_bf16((a), (b), (c), 0, 0, 0)
#define GLOAD16(gp, lp)                                                        \
  __builtin_amdgcn_global_load_lds(                                            \
      (const __attribute__((address_space(1))) void*)(gp),                     \
      (__attribute__((address_space(3))) void*)(lp), 16, 0, 0)

__device__ __forceinline__ unsigned short f2bf(float f) {
  unsigned u = __builtin_bit_cast(unsigned, f);
  u += 0x7FFFu + ((u >> 16) & 1u);
  return (unsigned short)(u >> 16);
}

__device__ __forceinline__ float fexp2(float x) {
  float r;
  asm("v_exp_f32 %0, %1" : "=v"(r) : "v"(x));
  return r;
}

// dst.lo = bf16(a), dst.hi = bf16(b)  (RNE, identical to f2bf)
__device__ __forceinline__ unsigned cvtpk(float a, float b) {
  unsigned r;
  asm("v_cvt_pk_bf16_f32 %0, %1, %2" : "=v"(r) : "v"(a), "v"(b));
  return r;
}

// ---------------- merged prologue: cast + both weight transposes ----------
__global__ __launch_bounds__(256) void c_prep(const float* __restrict__ hs,
                                              unsigned short* __restrict__ hsb,
                                              const float* __restrict__ wqkv,
                                              unsigned short* __restrict__ wqt,
                                              const float* __restrict__ wout,
                                              unsigned short* __restrict__ wot) {
  __shared__ float T[64][65];
  const int bid = blockIdx.x;
  const int t = threadIdx.x;
  if (bid < 4096) {
    int i = bid * 256 + t;
    const float4* p = reinterpret_cast<const float4*>(hs) + (size_t)i * 2;
    float4 a = p[0], b = p[1];
    u32x4 o;
    o[0] = cvtpk(a.x, a.y);
    o[1] = cvtpk(a.z, a.w);
    o[2] = cvtpk(b.x, b.y);
    o[3] = cvtpk(b.z, b.w);
    *reinterpret_cast<u32x4*>(&hsb[(size_t)i * 8]) = o;
    return;
  }
  const float* in;
  unsigned short* out;
  int R = 1024, C, idx;
  if (bid < 4864) { idx = bid - 4096; in = wqkv; out = wqt; C = 3072; }
  else            { idx = bid - 4864; in = wout; out = wot; C = 1024; }
  const int nbc = C >> 6;
  const int c0 = (idx % nbc) * 64, r0 = (idx / nbc) * 64;
  const int tr = t >> 4, tc = (t & 15) * 4;
#pragma unroll
  for (int i = 0; i < 4; ++i) {
    int r = tr + i * 16;
    float4 v = *reinterpret_cast<const float4*>(&in[(size_t)(r0 + r) * C + c0 + tc]);
    T[r][tc] = v.x; T[r][tc + 1] = v.y; T[r][tc + 2] = v.z; T[r][tc + 3] = v.w;
  }
  __syncthreads();
#pragma unroll
  for (int i = 0; i < 4; ++i) {
    int c = tr + i * 16;
    u32x2 o;
    o[0] = cvtpk(T[tc + 0][c], T[tc + 1][c]);
    o[1] = cvtpk(T[tc + 2][c], T[tc + 3][c]);
    *reinterpret_cast<u32x2*>(&out[(size_t)(c0 + c) * R + r0 + tc]) = o;
  }
}

// ---------------- Kernel 1: QKV projection GEMM (round-13, known-best) ----
// Q pre-scaled by 0.125*log2(e). V stored TRANSPOSED + quad-PAIRED:
// Vt[bh][d][pos(s)], pair p holds quads [q, q+4] adjacently (16B).
// 2-slot double buffer, 1 barrier per K-tile. 1D grid 1536, XCD-swizzled.
__global__ __launch_bounds__(256) void k_qkv(const unsigned short* __restrict__ A,
                                             const unsigned short* __restrict__ Bt,
                                             unsigned short* __restrict__ Qo,
                                             unsigned short* __restrict__ Ko,
                                             unsigned short* __restrict__ Vo) {
  __shared__ unsigned short As[2][128 * 32];
  __shared__ unsigned short Bs[2][128 * 32];
  const int t = threadIdx.x;
  const int lane = t & 63, wid = t >> 6;
  const int wr = wid >> 1, wc = wid & 1;
  const int cl = lane & 15, kr8 = (lane >> 4) << 3;
  const int id = blockIdx.x;
  const int s = (id & 7) * 192 + (id >> 3);
  const int m0 = (s / 24) << 7, n0 = (s % 24) << 7;

  f4 acc[4][4];
#pragma unroll
  for (int i = 0; i < 4; ++i)
#pragma unroll
    for (int j = 0; j < 4; ++j) acc[i][j] = (f4){0.f, 0.f, 0.f, 0.f};

  auto STAGE = [&](int buf, int kt) {
    int k0 = kt << 5;
#pragma unroll
    for (int it = 0; it < 2; ++it) {
      int c = t + (it << 8);
      int wb = (t & 192) + (it << 8);
      GLOAD16(A + (size_t)(m0 + (c >> 2)) * 1024 + k0 + ((c & 3) << 3),
              (char*)As[buf] + (size_t)wb * 16);
      GLOAD16(Bt + (size_t)(n0 + (c >> 2)) * 1024 + k0 + ((c & 3) << 3),
              (char*)Bs[buf] + (size_t)wb * 16);
    }
  };

  STAGE(0, 0);
  __syncthreads();
  for (int kt = 0; kt < 32; ++kt) {
    int cur = kt & 1;
    if (kt < 31) STAGE(cur ^ 1, kt + 1);
    const unsigned short* as = As[cur];
    const unsigned short* bs = Bs[cur];
    bf8 af[4], bfr[4];
#pragma unroll
    for (int mi = 0; mi < 4; ++mi)
      af[mi] = *reinterpret_cast<const bf8*>(&as[(wr * 64 + mi * 16 + cl) * 32 + kr8]);
#pragma unroll
    for (int ni = 0; ni < 4; ++ni)
      bfr[ni] = *reinterpret_cast<const bf8*>(&bs[(wc * 64 + ni * 16 + cl) * 32 + kr8]);
#pragma unroll
    for (int mi = 0; mi < 4; ++mi)
#pragma unroll
      for (int ni = 0; ni < 4; ++ni)
        acc[mi][ni] = MFMA16(af[mi], bfr[ni], acc[mi][ni]);
    __syncthreads();
  }

#pragma unroll
  for (int mi = 0; mi < 4; ++mi) {
#pragma unroll
    for (int ni = 0; ni < 4; ++ni) {
      int gcol = n0 + wc * 64 + ni * 16 + cl;
      int grow0 = m0 + wr * 64 + mi * 16 + ((lane >> 4) << 2);
      int b = grow0 >> 11, s0 = grow0 & 2047;
      if (gcol < 1024) {
        int h = gcol >> 6, hd = gcol & 63;
#pragma unroll
        for (int r = 0; r < 4; ++r)
          Qo[((size_t)(b * 16 + h) * 2048 + s0 + r) * 64 + hd] =
              f2bf(acc[mi][ni][r] * 0.18033688011112042f);  // 0.125*log2(e)
      } else if (gcol < 2048) {
        int cc = gcol - 1024;
        int h = cc >> 6, hd = cc & 63;
#pragma unroll
        for (int r = 0; r < 4; ++r)
          Ko[((size_t)(b * 16 + h) * 2048 + s0 + r) * 64 + hd] = f2bf(acc[mi][ni][r]);
      } else {
        int cc = gcol - 2048;
        int h = cc >> 6, hd = cc & 63;
        us4 o;
        o[0] = f2bf(acc[mi][ni][0]); o[1] = f2bf(acc[mi][ni][1]);
        o[2] = f2bf(acc[mi][ni][2]); o[3] = f2bf(acc[mi][ni][3]);
        // quad-pair interleave: pair p holds quads (8kg+gg, 8kg+gg+4).
        int q = (s0 >> 2) & 15;
        int kg2 = q >> 3, w = q & 7;
        int first = (w < 4) ? 1 : 0;
        int gg = first ? w : (w - 4);
        int p = 4 * kg2 + gg;
        int npos = (s0 & ~63) | (p << 3) | (first ? 0 : 4);
        *reinterpret_cast<us4*>(&Vo[((size_t)(b * 16 + h) * 64 + hd) * 2048 + npos]) = o;
      }
    }
  }
}

// ---------------- Kernel 2: flash attention (round-13, frozen) ------------
__global__ __launch_bounds__(512) void k_attn(const unsigned short* __restrict__ Q,
                                              const unsigned short* __restrict__ K,
                                              const unsigned short* __restrict__ Vt,
                                              unsigned short* __restrict__ Ctx) {
  __shared__ __align__(16) unsigned short SMEM[4][2][64 * 64];  // [slot][K/V]
  __shared__ float RedS[128];
  const int t = threadIdx.x;
  const int lane = t & 63, wid = t >> 6;
  const int cl = lane & 15, g = lane >> 4;
  const int qg = wid >> 1, kg = wid & 1;
  const int id = blockIdx.x;
  const int sw = (id & 7) * 128 + (id >> 3);
  const int bh = sw >> 4, qb = sw & 15;
  const int b = bh >> 4, h = bh & 15;
  const int q0 = qb << 7;
  const size_t base = (size_t)bh * (2048 * 64);

  bf8 qf[2][2];
#pragma unroll
  for (int qi = 0; qi < 2; ++qi) {
    int qrow = q0 + qg * 32 + qi * 16 + cl;
    qf[qi][0] = *reinterpret_cast<const bf8*>(&Q[base + (size_t)qrow * 64 + (g << 3)]);
    qf[qi][1] = *reinterpret_cast<const bf8*>(&Q[base + (size_t)qrow * 64 + 32 + (g << 3)]);
  }

  const unsigned ones_u = 0x3F803F80u;
  u32x4 ones4 = (u32x4){ones_u, ones_u, ones_u, ones_u};
  bf8 onesb = __builtin_bit_cast(bf8, ones4);
  const f4 minit = (f4){-12.f, -12.f, -12.f, -12.f};

  f4 o[2][4], osum[2];
#pragma unroll
  for (int qi = 0; qi < 2; ++qi) {
#pragma unroll
    for (int n = 0; n < 4; ++n) o[qi][n] = (f4){0.f, 0.f, 0.f, 0.f};
    osum[qi] = (f4){0.f, 0.f, 0.f, 0.f};
  }

  auto STAGEK = [&](int slot, int kv0) {
    int kvl = t >> 3;
    int dblk = (t & 7) ^ (kvl & 7);
    GLOAD16(K + base + (size_t)(kv0 + kvl) * 64 + (dblk << 3),
            (char*)SMEM[slot][0] + (size_t)(t & 448) * 16);
  };
  auto STAGEV = [&](int slot, int kv0) {
    int d = t >> 3, sp = t & 7;
    int p = sp ^ (d & 7);
    GLOAD16(Vt + base + (size_t)d * 2048 + kv0 + (p << 3),
            (char*)SMEM[slot][1] + (size_t)(t & 448) * 16);
  };

  auto COMPUTE = [&](const char* kp, const char* vp) {
    f4 sT[2][2];
    __builtin_amdgcn_s_setprio(1);
#pragma unroll
    for (int cb = 0; cb < 2; ++cb) {
      int row = (2 * kg + cb) * 16 + cl;
      bf8 a0 = *reinterpret_cast<const bf8*>(kp + row * 128 + ((g ^ (cl & 7)) << 4));
      bf8 a1 = *reinterpret_cast<const bf8*>(kp + row * 128 + (((4 + g) ^ (cl & 7)) << 4));
#pragma unroll
      for (int qi = 0; qi < 2; ++qi) {
        f4 s = minit;
        s = MFMA16(a0, qf[qi][0], s);
        s = MFMA16(a1, qf[qi][1], s);
        sT[cb][qi] = s;
      }
    }
    __builtin_amdgcn_s_setprio(0);

    u32x4 pw[2];
#pragma unroll
    for (int qi = 0; qi < 2; ++qi) {
      pw[qi][0] = cvtpk(fexp2(sT[0][qi][0]), fexp2(sT[0][qi][1]));
      pw[qi][1] = cvtpk(fexp2(sT[0][qi][2]), fexp2(sT[0][qi][3]));
      pw[qi][2] = cvtpk(fexp2(sT[1][qi][0]), fexp2(sT[1][qi][1]));
      pw[qi][3] = cvtpk(fexp2(sT[1][qi][2]), fexp2(sT[1][qi][3]));
    }
    bf8 pa0 = __builtin_bit_cast(bf8, pw[0]);
    bf8 pa1 = __builtin_bit_cast(bf8, pw[1]);

    const unsigned vb = (unsigned)(cl * 128) + (unsigned)(((4 * kg + g) ^ (cl & 7)) << 4);
    __builtin_amdgcn_s_setprio(1);
#pragma unroll
    for (int n = 0; n < 4; ++n) {
      bf8 vb8 = *reinterpret_cast<const bf8*>(vp + vb + n * 2048);
      o[0][n] = MFMA16(pa0, vb8, o[0][n]);
      o[1][n] = MFMA16(pa1, vb8, o[1][n]);
    }
    osum[0] = MFMA16(pa0, onesb, osum[0]);
    osum[1] = MFMA16(pa1, onesb, osum[1]);
    __builtin_amdgcn_s_setprio(0);
  };

  STAGEK(0, 0);
  STAGEV(0, 0);
  STAGEK(1, 64);
  STAGEV(1, 64);
  __syncthreads();

  for (int ti = 0; ti < 16; ++ti) {
    int t0 = 2 * ti, t1 = t0 + 1;
    if (ti < 15) {
      STAGEK((t0 + 2) & 3, (t0 + 2) << 6);
      STAGEV((t0 + 2) & 3, (t0 + 2) << 6);
      STAGEK((t1 + 2) & 3, (t1 + 2) << 6);
      STAGEV((t1 + 2) & 3, (t1 + 2) << 6);
    }
    COMPUTE((const char*)SMEM[t0 & 3][0], (const char*)SMEM[t0 & 3][1]);
    COMPUTE((const char*)SMEM[t1 & 3][0], (const char*)SMEM[t1 & 3][1]);
    __syncthreads();
  }

  float* red = (float*)SMEM;
  if (kg) {
#pragma unroll
    for (int qi = 0; qi < 2; ++qi) {
#pragma unroll
      for (int n = 0; n < 4; ++n) {
        int ridx = qg * 8 + qi * 4 + n;
        *reinterpret_cast<f4*>(red + ridx * 256 + cl * 16 + g * 4) = o[qi][n];
      }
      if (cl == 0)
        *reinterpret_cast<f4*>(&RedS[(qg * 2 + qi) * 16 + g * 4]) = osum[qi];
    }
  }
  __syncthreads();
  if (!kg) {
#pragma unroll
    for (int qi = 0; qi < 2; ++qi) {
#pragma unroll
      for (int n = 0; n < 4; ++n) {
        int ridx = qg * 8 + qi * 4 + n;
        f4 po = *reinterpret_cast<const f4*>(red + ridx * 256 + cl * 16 + g * 4);
        o[qi][n] += po;
      }
      f4 ps = *reinterpret_cast<const f4*>(&RedS[(qg * 2 + qi) * 16 + g * 4]);
      osum[qi] += ps;
#pragma unroll
      for (int r = 0; r < 4; ++r) {
        float inv = 1.0f / osum[qi][r];
        int sq = q0 + qg * 32 + qi * 16 + (g << 2) + r;
        size_t rb = ((size_t)b * 2048 + sq) * 1024 + h * 64;
#pragma unroll
        for (int n = 0; n < 4; ++n) Ctx[rb + n * 16 + cl] = f2bf(o[qi][n][r] * inv);
      }
    }
  }
}

// ---------------- Kernel 3: output projection GEMM (round-13, frozen) -----
__global__ __launch_bounds__(256) void k_oproj(const unsigned short* __restrict__ A,
                                               const unsigned short* __restrict__ Bt,
                                               float* __restrict__ Out) {
  __shared__ unsigned short As[2][128 * 32];
  __shared__ unsigned short Bs[2][128 * 32];
  const int t = threadIdx.x;
  const int lane = t & 63, wid = t >> 6;
  const int wr = wid >> 1, wc = wid & 1;
  const int cl = lane & 15, kr8 = (lane >> 4) << 3;
  const int id = blockIdx.x;
  const int s = (id & 7) * 64 + (id >> 3);
  const int m0 = (s >> 3) << 7, n0 = (s & 7) << 7;

  f4 acc[4][4];
#pragma unroll
  for (int i = 0; i < 4; ++i)
#pragma unroll
    for (int j = 0; j < 4; ++j) acc[i][j] = (f4){0.f, 0.f, 0.f, 0.f};

  auto STAGE = [&](int buf, int kt) {
    int k0 = kt << 5;
#pragma unroll
    for (int it = 0; it < 2; ++it) {
      int c = t + (it << 8);
      int wb = (t & 192) + (it << 8);
      GLOAD16(A + (size_t)(m0 + (c >> 2)) * 1024 + k0 + ((c & 3) << 3),
              (char*)As[buf] + (size_t)wb * 16);
      GLOAD16(Bt + (size_t)(n0 + (c >> 2)) * 1024 + k0 + ((c & 3) << 3),
              (char*)Bs[buf] + (size_t)wb * 16);
    }
  };

  STAGE(0, 0);
  __syncthreads();
  for (int kt = 0; kt < 32; ++kt) {
    int cur = kt & 1;
    if (kt < 31) STAGE(cur ^ 1, kt + 1);
    const unsigned short* as = As[cur];
    const unsigned short* bs = Bs[cur];
    bf8 af[4], bfr[4];
#pragma unroll
    for (int mi = 0; mi < 4; ++mi)
      af[mi] = *reinterpret_cast<const bf8*>(&as[(wr * 64 + mi * 16 + cl) * 32 + kr8]);
#pragma unroll
    for (int ni = 0; ni < 4; ++ni)
      bfr[ni] = *reinterpret_cast<const bf8*>(&bs[(wc * 64 + ni * 16 + cl) * 32 + kr8]);
#pragma unroll
    for (int mi = 0; mi < 4; ++mi)
#pragma unroll
      for (int ni = 0; ni < 4; ++ni)
        acc[mi][ni] = MFMA16(af[mi], bfr[ni], acc[mi][ni]);
    __syncthreads();
  }

#pragma unroll
  for (int mi = 0; mi < 4; ++mi) {
#pragma unroll
    for (int ni = 0; ni < 4; ++ni) {
      int gcol = n0 + wc * 64 + ni * 16 + cl;
#pragma unroll
      for (int r = 0; r < 4; ++r) {
        int grow = m0 + wr * 64 + mi * 16 + ((lane >> 4) << 2) + r;
        Out[(size_t)grow * 1024 + gcol] = acc[mi][ni][r];
      }
    }
  }
}

extern "C" void kernel_launch(void* const* d_in, const int* in_sizes, int n_in,
                              void* d_out, int out_size, void* d_ws, size_t ws_size,
                              hipStream_t stream) {
  const float* hs = (const float*)d_in[0];
  const float* wqkv = (const float*)d_in[1];
  const float* wout = (const float*)d_in[2];
  float* out = (float*)d_out;

  unsigned short* ws = (unsigned short*)d_ws;
  const size_t NHS = (size_t)8192 * 1024;
  const size_t NWQ = (size_t)1024 * 3072;
  const size_t NWO = (size_t)1024 * 1024;
  const size_t NQ = (size_t)64 * 2048 * 64;

  unsigned short* hsb = ws;
  unsigned short* wqt = ws + NHS;
  unsigned short* wot = wqt + NWQ;
  unsigned short* Qw = wot + NWO;
  unsigned short* Kw = Qw + NQ;
  unsigned short* Vw = Kw + NQ;   // Vt layout [bh][64][2048], quad-paired
  unsigned short* Cw = hsb;       // hs dead after k_qkv

  c_prep<<<dim3(5120), 256, 0, stream>>>(hs, hsb, wqkv, wqt, wout, wot);
  k_qkv<<<dim3(1536), 256, 0, stream>>>(hsb, wqt, Qw, Kw, Vw);
  k_attn<<<dim3(1024), 512, 0, stream>>>(Qw, Kw, Vw, Cw);
  k_oproj<<<dim3(512), 256, 0, stream>>>(Cw, wot, out);
}